// Round 7
// baseline (67.680 us; speedup 1.0000x reference)
//
#include <hip/hip_runtime.h>
#include <hip/hip_bf16.h>

// Sparse self-attention == dense attention within each residue class (mod 4)
// + 7-wide window (duplicate entries => logit += 1.0 in log2 space)
// + OOB window slots adding exp2(0)=1 to the denominator
// + the zero key n=1024 folded into the epilogue denominator (never staged).
// prep (x->bf16, W transpose) -> fused QKV GEMM (XCD-chunked grid) ->
// flash attn: 32x32 MFMA, swapped QK^T (S^T, q lane-local), P kept fully
// in-register (cvt_pk + shfl_xor(32)), gload_lds double-buffer.

#define BATCH 2
#define LSEQ  4096
#define DMODEL 512
#define NH    8
#define DHEAD 64
#define NPAD  1088      // K/V row stride (valid rows 0..1023; tails never touched)
#define QSCALE 0.18033688011112042f   // 0.125 * log2(e)

typedef __bf16 bf16x8 __attribute__((ext_vector_type(8)));
typedef __attribute__((ext_vector_type(4))) float f32x4;
typedef __attribute__((ext_vector_type(16))) float f32x16;
typedef unsigned short u16;
typedef unsigned int u32;
typedef __attribute__((ext_vector_type(8))) u16 u16x8;
typedef __attribute__((ext_vector_type(4))) u16 u16x4;
typedef __attribute__((ext_vector_type(4))) u32 u32x4;

__device__ __forceinline__ u16 f2bf(float f) {
    u32 u = __float_as_uint(f);
    u += 0x7fffu + ((u >> 16) & 1u);   // RNE, finite inputs
    return (u16)(u >> 16);
}

__device__ __forceinline__ u32 cvtpk(float lo, float hi) {
    u32 d;
    asm("v_cvt_pk_bf16_f32 %0, %1, %2" : "=v"(d) : "v"(lo), "v"(hi));
    return d;
}

__device__ __forceinline__ void gload16(const u16* g, u16* l) {
    __builtin_amdgcn_global_load_lds(
        (const __attribute__((address_space(1))) u32*)(const void*)g,
        (__attribute__((address_space(3))) u32*)(void*)l, 16, 0, 0);
}

__device__ __forceinline__ f32x16 zero16() {
    f32x16 v;
    #pragma unroll
    for (int i = 0; i < 16; ++i) v[i] = 0.f;
    return v;
}

// ---------------------------------------------------------------------------
// prep: bid<2048: xb = bf16(x);  2048..2239: Wt[c][k] = bf16(W[k][c]) transposed
// ---------------------------------------------------------------------------
__global__ __launch_bounds__(256) void prep_kernel(
    const float* __restrict__ x,
    const float* __restrict__ Wq, const float* __restrict__ Wk, const float* __restrict__ Wv,
    u16* __restrict__ xb, u16* __restrict__ Wt)
{
    const int bid = blockIdx.x, tid = threadIdx.x;
    if (bid < 2048) {
        const size_t i0 = (size_t)bid * 2048 + (size_t)tid * 8;
        float4 a = *(const float4*)(x + i0);
        float4 b = *(const float4*)(x + i0 + 4);
        u16x8 o = { f2bf(a.x), f2bf(a.y), f2bf(a.z), f2bf(a.w),
                    f2bf(b.x), f2bf(b.y), f2bf(b.z), f2bf(b.w) };
        *(u16x8*)(xb + i0) = o;
    } else {
        const int wb  = bid - 2048;            // 0..191
        const int mat = wb >> 6;
        const int t   = wb & 63;
        const int k0  = (t >> 3) * 64, c0 = (t & 7) * 64;
        const float* W = (mat == 0) ? Wq : (mat == 1) ? Wk : Wv;
        __shared__ u16 Ws[64][72];             // [k][c]
        #pragma unroll
        for (int i = 0; i < 4; ++i) {
            const int chunk = i * 256 + tid;
            const int kr = chunk >> 4, c4 = (chunk & 15) * 4;
            float4 v = *(const float4*)(W + (size_t)(k0 + kr) * DMODEL + c0 + c4);
            u16x4 q = { f2bf(v.x), f2bf(v.y), f2bf(v.z), f2bf(v.w) };
            *(u16x4*)&Ws[kr][c4] = q;
        }
        __syncthreads();
        const int cc = tid >> 2, kq = (tid & 3) * 16;
        alignas(16) u16 tmp[16];
        #pragma unroll
        for (int kk = 0; kk < 16; ++kk) tmp[kk] = Ws[kq + kk][cc];
        u16* dst = Wt + (size_t)(mat * 512 + c0 + cc) * DMODEL + k0 + kq;
        *(u16x8*)dst       = *(const u16x8*)&tmp[0];
        *(u16x8*)(dst + 8) = *(const u16x8*)&tmp[8];
    }
}

// ---------------------------------------------------------------------------
// Fused QKV GEMM: C = xb(8192x512) * Wt^T(512x1536), BM=BN=128, BK=64, 4 waves.
// 1-D grid, XCD-chunked for L2 residency of A slices.
// nt 0-3 -> Q (scaled), 4-7 -> K, 8-11 -> V (written transposed via LDS retile).
// ---------------------------------------------------------------------------
__global__ __launch_bounds__(256) void gemm_kernel(
    const u16* __restrict__ xb, const u16* __restrict__ Wt,
    u16* __restrict__ Qb, u16* __restrict__ Kb, u16* __restrict__ Vb)
{
    const int bid = blockIdx.x;
    const int xcd = bid & 7;
    const int j   = bid >> 3;            // 0..95
    const int mt  = xcd * 8 + (j / 12);  // 0..63
    const int nt  = j % 12;
    const int m0 = mt * 128;
    const int n0 = nt * 128;
    const int tid = threadIdx.x;
    const int w = tid >> 6, l = tid & 63, lr = l & 15, lh = l >> 4;
    const int wr = w >> 1, wc = w & 1;

    __shared__ u16 smem[16896];     // A:[0,8192) B:[8192,16384); V-retile 128*132
    u16* As = smem;
    u16* Bs = smem + 8192;

    f32x4 acc[4][4];
    const f32x4 fzero = {0.f, 0.f, 0.f, 0.f};
    #pragma unroll
    for (int mi = 0; mi < 4; ++mi)
        #pragma unroll
        for (int nj = 0; nj < 4; ++nj) acc[mi][nj] = fzero;

    for (int kt = 0; kt < 8; ++kt) {
        const int k0 = kt * 64;
        #pragma unroll
        for (int i = 0; i < 4; ++i) {
            const int cid = i * 256 + tid;
            const int row = cid >> 3, ch = cid & 7;
            const int sch = ch ^ (row & 7);
            u16* dstA = As + (i * 256 + w * 64) * 8;   // wave-uniform base
            u16* dstB = Bs + (i * 256 + w * 64) * 8;
            gload16(xb + (size_t)(m0 + row) * DMODEL + k0 + sch * 8, dstA);
            gload16(Wt + (size_t)(n0 + row) * DMODEL + k0 + sch * 8, dstB);
        }
        __syncthreads();

        #pragma unroll
        for (int kk = 0; kk < 2; ++kk) {
            const int cs = (kk * 4 + lh) ^ (lr & 7);   // swizzled chunk
            bf16x8 af[4], bfr[4];
            #pragma unroll
            for (int mi = 0; mi < 4; ++mi)
                af[mi] = *(const bf16x8*)(As + (wr * 64 + mi * 16 + lr) * 64 + cs * 8);
            #pragma unroll
            for (int nj = 0; nj < 4; ++nj)
                bfr[nj] = *(const bf16x8*)(Bs + (wc * 64 + nj * 16 + lr) * 64 + cs * 8);
            #pragma unroll
            for (int mi = 0; mi < 4; ++mi)
                #pragma unroll
                for (int nj = 0; nj < 4; ++nj)
                    acc[mi][nj] = __builtin_amdgcn_mfma_f32_16x16x32_bf16(af[mi], bfr[nj], acc[mi][nj], 0, 0, 0);
        }
        __syncthreads();
    }

    const int mat = nt >> 2;
    const int hp  = nt & 3;
    if (mat < 2) {
        u16* Ob = (mat == 0) ? Qb : Kb;
        const float osc = (mat == 0) ? QSCALE : 1.0f;
        #pragma unroll
        for (int mi = 0; mi < 4; ++mi) {
            const int gmb = m0 + wr * 64 + mi * 16 + lh * 4;
            const int b = gmb >> 12;
            #pragma unroll
            for (int rr = 0; rr < 4; ++rr) {
                const int t = (gmb + rr) & 4095;
                const int n = t >> 2, r = t & 3;
                #pragma unroll
                for (int nj = 0; nj < 4; ++nj) {
                    const int c  = wc * 64 + nj * 16 + lr;
                    const int h  = hp * 2 + (c >> 6);
                    const int dk = c & 63;
                    const size_t g = ((size_t)(b * NH + h)) * 4 + r;
                    Ob[(g * NPAD + n) * DHEAD + dk] = f2bf(acc[mi][nj][rr] * osc);
                }
            }
        }
    } else {
        // V: retile via LDS -> coalesced stores of V^T [g][dv][n]
        #pragma unroll
        for (int mi = 0; mi < 4; ++mi) {
            const int nrel = wr * 16 + mi * 4 + lh;
            #pragma unroll
            for (int nj = 0; nj < 4; ++nj) {
                const int c = wc * 64 + nj * 16 + lr;
                #pragma unroll
                for (int rr = 0; rr < 4; ++rr)
                    smem[c * 132 + rr * 32 + nrel] = f2bf(acc[mi][nj][rr]);
            }
        }
        __syncthreads();
        const int b  = m0 >> 12;
        const int nb = (m0 & 4095) >> 2;
        #pragma unroll
        for (int e = 0; e < 2; ++e) {
            const int chunk = e * 256 + tid;
            const int c = chunk & 127, r = chunk >> 7;
            const int h  = hp * 2 + (c >> 6);
            const int dv = c & 63;
            const size_t g = ((size_t)(b * NH + h)) * 4 + r;
            u16* dst = Vb + (g * DHEAD + dv) * NPAD + nb;
            const u16* src = smem + c * 132 + r * 32;
            alignas(16) u16 tmp[32];
            #pragma unroll
            for (int q8 = 0; q8 < 8; ++q8)
                *(u16x4*)&tmp[q8 * 4] = *(const u16x4*)(src + q8 * 4);
            #pragma unroll
            for (int q16 = 0; q16 < 4; ++q16)
                *(u16x8*)(dst + q16 * 8) = *(const u16x8*)&tmp[q16 * 8];
        }
    }
}

// ---------------------------------------------------------------------------
// Flash attention per (b,h,r): 128 queries/block, 4 waves x 32 q-rows,
// 32x32x16 MFMA, swapped QK^T => q is lane-local; P stays in registers.
// ---------------------------------------------------------------------------
__global__ __launch_bounds__(256) void attn_kernel(
    const u16* __restrict__ Qb, const u16* __restrict__ Kb, const u16* __restrict__ Vb,
    float* __restrict__ out)
{
    const int g  = blockIdx.x;          // ((b*8+h)*4+r): blocks sharing g -> same XCD
    const int b  = g >> 5;
    const int h  = (g >> 2) & 7;
    const int r  = g & 3;
    const int q0 = blockIdx.y * 128;
    const int tid = threadIdx.x;
    const int w  = tid >> 6;            // 0..3
    const int l  = tid & 63;
    const int lr = l & 31;              // q within wave tile / dv / key row
    const int hi = l >> 5;              // half-wave

    const u16* Qg  = Qb + (size_t)g * NPAD * DHEAD;
    const u16* Kg  = Kb + (size_t)g * NPAD * DHEAD;
    const u16* Vtg = Vb + (size_t)g * DHEAD * NPAD;   // [dv][n]

    __shared__ u16 KV[2][2][4096];   // [buf][K/V][64 rows][8 slots][8 u16]

    // staging: 256 thr cover rows 0-31; second gload covers rows 32-63.
    const int srow = tid >> 3;              // 0..31
    const int ssch = (tid & 7) ^ (srow & 7);
    const u16* ksrc0 = Kg  + (size_t)srow * DHEAD + ssch * 8;
    const u16* vsrc0 = Vtg + (size_t)srow * NPAD  + ssch * 8;

    // Q fragments: lane -> q-row q0 + w*32 + lr, k-chunk c*16 + hi*8
    bf16x8 qa[4];
    {
        const u16* qrow = Qg + (size_t)(q0 + w * 32 + lr) * DHEAD + hi * 8;
        qa[0] = *(const bf16x8*)(qrow);
        qa[1] = *(const bf16x8*)(qrow + 16);
        qa[2] = *(const bf16x8*)(qrow + 32);
        qa[3] = *(const bf16x8*)(qrow + 48);
    }

    f32x16 o0 = zero16(), o1 = zero16();
    float Lown = 0.f;
    const int qw0 = q0 + w * 32;
    const int qg  = qw0 + lr;

    // prologue: stage tile 0 into buf 0
    gload16(ksrc0,              &KV[0][0][w * 512]);
    gload16(ksrc0 + 32 * DHEAD, &KV[0][0][2048 + w * 512]);
    gload16(vsrc0,              &KV[0][1][w * 512]);
    gload16(vsrc0 + 32 * NPAD,  &KV[0][1][2048 + w * 512]);

    for (int mt = 0; mt < 16; ++mt) {
        const int cur = mt & 1;
        if (mt < 15) {
            const size_t ko = (size_t)(mt + 1) * 64 * DHEAD;
            const int    vo = (mt + 1) * 64;
            gload16(ksrc0 + ko,              &KV[cur ^ 1][0][w * 512]);
            gload16(ksrc0 + ko + 32 * DHEAD, &KV[cur ^ 1][0][2048 + w * 512]);
            gload16(vsrc0 + vo,              &KV[cur ^ 1][1][w * 512]);
            gload16(vsrc0 + vo + 32 * NPAD,  &KV[cur ^ 1][1][2048 + w * 512]);
            asm volatile("s_waitcnt vmcnt(4)" ::: "memory");
        } else {
            asm volatile("s_waitcnt vmcnt(0)" ::: "memory");
        }
        __builtin_amdgcn_s_barrier();

        const u16* Kbuf = KV[cur][0];
        const u16* Vbuf = KV[cur][1];

        // S^T = K Q^T : A = K-frag (rows=keys), B = Q-frag (cols=q)
        f32x16 sA = zero16(), sB = zero16();   // keys 0-31 / 32-63
        __builtin_amdgcn_s_setprio(1);
        #pragma unroll
        for (int c = 0; c < 4; ++c) {
            const int slot = (c * 2 + hi) ^ (lr & 7);
            bf16x8 kbA = *(const bf16x8*)(Kbuf + (lr * 8 + slot) * 8);
            bf16x8 kbB = *(const bf16x8*)(Kbuf + ((32 + lr) * 8 + slot) * 8);
            sA = __builtin_amdgcn_mfma_f32_32x32x16_bf16(kbA, qa[c], sA, 0, 0, 0);
            sB = __builtin_amdgcn_mfma_f32_32x32x16_bf16(kbB, qa[c], sB, 0, 0, 0);
        }
        __builtin_amdgcn_s_setprio(0);

        // softmax terms (fixed M=0, log2 space): p = exp2(s [+1 in window])
        const int m0 = mt * 64;
        const bool special = (m0 + 66 >= qw0) && (m0 <= qw0 + 34);
        if (!special) {
            #pragma unroll
            for (int reg = 0; reg < 16; ++reg) {
                sA[reg] = __builtin_amdgcn_exp2f(sA[reg]);
                sB[reg] = __builtin_amdgcn_exp2f(sB[reg]);
                Lown += sA[reg] + sB[reg];
            }
        } else {
            #pragma unroll
            for (int reg = 0; reg < 16; ++reg) {
                const int krel = (reg & 3) + 8 * (reg >> 2) + 4 * hi;
                {
                    const int dd = m0 + krel - qg;
                    float v = sA[reg];
                    if (dd >= -3 && dd <= 3) v += 1.0f;
                    sA[reg] = __builtin_amdgcn_exp2f(v);
                }
                {
                    const int dd = m0 + 32 + krel - qg;
                    float v = sB[reg];
                    if (dd >= -3 && dd <= 3) v += 1.0f;
                    sB[reg] = __builtin_amdgcn_exp2f(v);
                }
                Lown += sA[reg] + sB[reg];
            }
        }

        // pack P to bf16 pairs (keys 2k, 2k+1 within each half)
        u32 pkA[8], pkB[8];
        #pragma unroll
        for (int r2 = 0; r2 < 8; ++r2) {
            pkA[r2] = cvtpk(sA[2 * r2], sA[2 * r2 + 1]);
            pkB[r2] = cvtpk(sB[2 * r2], sB[2 * r2 + 1]);
        }

        // PV: assemble A-frag (P) in-register, B = V-frag from LDS
        __builtin_amdgcn_s_setprio(1);
        #pragma unroll
        for (int c = 0; c < 4; ++c) {
            const int c1 = c & 1;
            u32 p0, p1, p2, p3;                 // pk(base), pk(base+2), pk(base+4), pk(base+6)
            if (c < 2) { p0 = pkA[4*c1]; p1 = pkA[4*c1+1]; p2 = pkA[4*c1+2]; p3 = pkA[4*c1+3]; }
            else       { p0 = pkB[4*c1]; p1 = pkB[4*c1+1]; p2 = pkB[4*c1+2]; p3 = pkB[4*c1+3]; }
            const u32 own0  = hi ? p2 : p0;
            const u32 own1  = hi ? p3 : p1;
            const u32 send0 = hi ? p0 : p2;
            const u32 send1 = hi ? p1 : p3;
            const u32 recv0 = (u32)__shfl_xor((int)send0, 32);
            const u32 recv1 = (u32)__shfl_xor((int)send1, 32);
            u32x4 paw;
            paw.x = hi ? recv0 : own0;
            paw.y = hi ? recv1 : own1;
            paw.z = hi ? own0  : recv0;
            paw.w = hi ? own1  : recv1;
            const bf16x8 pa = __builtin_bit_cast(bf16x8, paw);

            const int slot = (c * 2 + hi) ^ (lr & 7);
            bf16x8 vb0 = *(const bf16x8*)(Vbuf + (lr * 8 + slot) * 8);          // dv 0-31
            bf16x8 vb1 = *(const bf16x8*)(Vbuf + ((32 + lr) * 8 + slot) * 8);   // dv 32-63
            o0 = __builtin_amdgcn_mfma_f32_32x32x16_bf16(pa, vb0, o0, 0, 0, 0);
            o1 = __builtin_amdgcn_mfma_f32_32x32x16_bf16(pa, vb1, o1, 0, 0, 0);
        }
        __builtin_amdgcn_s_setprio(0);
        __syncthreads();   // all waves done reading buf before next-iter writes
    }

    // epilogue: denominator = Lown(both halves) + zero-key (+1, doubled if
    // q>=1021) + OOB window slots (+coob); divide and store.
    const float Ltot = Lown + __shfl_xor(Lown, 32);
    const int coob = (qg < 3 ? 3 - qg : 0) + (qg > 1021 ? qg - 1021 : 0);
    const float inv = 1.0f / (Ltot + (float)(coob + 1 + (qg >= 1021 ? 1 : 0)));

    float iv[16];
    #pragma unroll
    for (int reg = 0; reg < 16; ++reg)
        iv[reg] = __shfl(inv, (reg & 3) + 8 * (reg >> 2) + 4 * hi);

    #pragma unroll
    for (int reg = 0; reg < 16; ++reg) {
        const int qrel = (reg & 3) + 8 * (reg >> 2) + 4 * hi;
        const int t = (q0 + w * 32 + qrel) * 4 + r;
        float* orow = out + ((size_t)b * LSEQ + t) * DMODEL + h * DHEAD;
        orow[lr]      = o0[reg] * iv[reg];
        orow[32 + lr] = o1[reg] * iv[reg];
    }
}

extern "C" void kernel_launch(void* const* d_in, const int* in_sizes, int n_in,
                              void* d_out, int out_size, void* d_ws, size_t ws_size,
                              hipStream_t stream) {
    const float* x  = (const float*)d_in[0];
    const float* Wq = (const float*)d_in[1];
    const float* Wk = (const float*)d_in[2];
    const float* Wv = (const float*)d_in[3];
    float* out = (float*)d_out;

    const size_t SZ = (size_t)BATCH * NH * 4 * NPAD * DHEAD;   // per-tensor elems
    u16* Qb = (u16*)d_ws;
    u16* Kb = Qb + SZ;
    u16* Vb = Kb + SZ;

    // scratch for bf16 x and transposed W lives in d_out (overwritten by attn)
    u16* xb = (u16*)d_out;                       // 8192*512 u16
    u16* Wt = xb + (size_t)8192 * 512;           // 1536*512 u16

    prep_kernel<<<2240, 256, 0, stream>>>(x, Wq, Wk, Wv, xb, Wt);

    gemm_kernel<<<768, 256, 0, stream>>>(xb, Wt, Qb, Kb, Vb);

    dim3 ga(64, 8);
    attn_kernel<<<ga, 256, 0, stream>>>(Qb, Kb, Vb, out);
}

// Round 8
// 67.666 us; speedup vs baseline: 1.0002x; 1.0002x over previous
//
#include <hip/hip_runtime.h>
#include <hip/hip_bf16.h>

// Sparse self-attention == dense attention within each residue class (mod 4)
// + 7-wide window (duplicate entries => logit += 1.0 in log2 space)
// + OOB window slots adding exp2(0)=1 to the denominator
// + the zero key n=1024 folded into the epilogue denominator (never staged).
// prep (x->bf16, W transpose) -> fused QKV GEMM (XCD-chunked grid) ->
// flash attn: 32x32 MFMA, swapped QK^T (S^T, q lane-local), P in-register
// (cvt_pk + shfl_xor(32)), gload_lds double-buffer, 8 waves/512thr/256q.

#define BATCH 2
#define LSEQ  4096
#define DMODEL 512
#define NH    8
#define DHEAD 64
#define NPAD  1088      // K/V row stride (valid rows 0..1023; tails never touched)
#define QSCALE 0.18033688011112042f   // 0.125 * log2(e)

typedef __bf16 bf16x8 __attribute__((ext_vector_type(8)));
typedef __attribute__((ext_vector_type(4))) float f32x4;
typedef __attribute__((ext_vector_type(16))) float f32x16;
typedef unsigned short u16;
typedef unsigned int u32;
typedef __attribute__((ext_vector_type(8))) u16 u16x8;
typedef __attribute__((ext_vector_type(4))) u16 u16x4;
typedef __attribute__((ext_vector_type(4))) u32 u32x4;

__device__ __forceinline__ u16 f2bf(float f) {
    u32 u = __float_as_uint(f);
    u += 0x7fffu + ((u >> 16) & 1u);   // RNE, finite inputs
    return (u16)(u >> 16);
}

__device__ __forceinline__ u32 cvtpk(float lo, float hi) {
    u32 d;
    asm("v_cvt_pk_bf16_f32 %0, %1, %2" : "=v"(d) : "v"(lo), "v"(hi));
    return d;
}

__device__ __forceinline__ void gload16(const u16* g, u16* l) {
    __builtin_amdgcn_global_load_lds(
        (const __attribute__((address_space(1))) u32*)(const void*)g,
        (__attribute__((address_space(3))) u32*)(void*)l, 16, 0, 0);
}

__device__ __forceinline__ f32x16 zero16() {
    f32x16 v;
    #pragma unroll
    for (int i = 0; i < 16; ++i) v[i] = 0.f;
    return v;
}

// ---------------------------------------------------------------------------
// prep: bid<2048: xb = bf16(x);  2048..2239: Wt[c][k] = bf16(W[k][c]) transposed
// ---------------------------------------------------------------------------
__global__ __launch_bounds__(256) void prep_kernel(
    const float* __restrict__ x,
    const float* __restrict__ Wq, const float* __restrict__ Wk, const float* __restrict__ Wv,
    u16* __restrict__ xb, u16* __restrict__ Wt)
{
    const int bid = blockIdx.x, tid = threadIdx.x;
    if (bid < 2048) {
        const size_t i0 = (size_t)bid * 2048 + (size_t)tid * 8;
        float4 a = *(const float4*)(x + i0);
        float4 b = *(const float4*)(x + i0 + 4);
        u16x8 o = { f2bf(a.x), f2bf(a.y), f2bf(a.z), f2bf(a.w),
                    f2bf(b.x), f2bf(b.y), f2bf(b.z), f2bf(b.w) };
        *(u16x8*)(xb + i0) = o;
    } else {
        const int wb  = bid - 2048;            // 0..191
        const int mat = wb >> 6;
        const int t   = wb & 63;
        const int k0  = (t >> 3) * 64, c0 = (t & 7) * 64;
        const float* W = (mat == 0) ? Wq : (mat == 1) ? Wk : Wv;
        __shared__ u16 Ws[64][72];             // [k][c]
        #pragma unroll
        for (int i = 0; i < 4; ++i) {
            const int chunk = i * 256 + tid;
            const int kr = chunk >> 4, c4 = (chunk & 15) * 4;
            float4 v = *(const float4*)(W + (size_t)(k0 + kr) * DMODEL + c0 + c4);
            u16x4 q = { f2bf(v.x), f2bf(v.y), f2bf(v.z), f2bf(v.w) };
            *(u16x4*)&Ws[kr][c4] = q;
        }
        __syncthreads();
        const int cc = tid >> 2, kq = (tid & 3) * 16;
        alignas(16) u16 tmp[16];
        #pragma unroll
        for (int kk = 0; kk < 16; ++kk) tmp[kk] = Ws[kq + kk][cc];
        u16* dst = Wt + (size_t)(mat * 512 + c0 + cc) * DMODEL + k0 + kq;
        *(u16x8*)dst       = *(const u16x8*)&tmp[0];
        *(u16x8*)(dst + 8) = *(const u16x8*)&tmp[8];
    }
}

// ---------------------------------------------------------------------------
// Fused QKV GEMM: C = xb(8192x512) * Wt^T(512x1536), BM=BN=128, BK=64, 4 waves.
// 1-D grid, XCD-chunked for L2 residency of A slices.
// nt 0-3 -> Q (scaled), 4-7 -> K, 8-11 -> V (written transposed via LDS retile).
// ---------------------------------------------------------------------------
__global__ __launch_bounds__(256) void gemm_kernel(
    const u16* __restrict__ xb, const u16* __restrict__ Wt,
    u16* __restrict__ Qb, u16* __restrict__ Kb, u16* __restrict__ Vb)
{
    const int bid = blockIdx.x;
    const int xcd = bid & 7;
    const int j   = bid >> 3;            // 0..95
    const int mt  = xcd * 8 + (j / 12);  // 0..63
    const int nt  = j % 12;
    const int m0 = mt * 128;
    const int n0 = nt * 128;
    const int tid = threadIdx.x;
    const int w = tid >> 6, l = tid & 63, lr = l & 15, lh = l >> 4;
    const int wr = w >> 1, wc = w & 1;

    __shared__ u16 smem[16896];     // A:[0,8192) B:[8192,16384); V-retile 128*132
    u16* As = smem;
    u16* Bs = smem + 8192;

    f32x4 acc[4][4];
    const f32x4 fzero = {0.f, 0.f, 0.f, 0.f};
    #pragma unroll
    for (int mi = 0; mi < 4; ++mi)
        #pragma unroll
        for (int nj = 0; nj < 4; ++nj) acc[mi][nj] = fzero;

    for (int kt = 0; kt < 8; ++kt) {
        const int k0 = kt * 64;
        #pragma unroll
        for (int i = 0; i < 4; ++i) {
            const int cid = i * 256 + tid;
            const int row = cid >> 3, ch = cid & 7;
            const int sch = ch ^ (row & 7);
            u16* dstA = As + (i * 256 + w * 64) * 8;   // wave-uniform base
            u16* dstB = Bs + (i * 256 + w * 64) * 8;
            gload16(xb + (size_t)(m0 + row) * DMODEL + k0 + sch * 8, dstA);
            gload16(Wt + (size_t)(n0 + row) * DMODEL + k0 + sch * 8, dstB);
        }
        __syncthreads();

        #pragma unroll
        for (int kk = 0; kk < 2; ++kk) {
            const int cs = (kk * 4 + lh) ^ (lr & 7);   // swizzled chunk
            bf16x8 af[4], bfr[4];
            #pragma unroll
            for (int mi = 0; mi < 4; ++mi)
                af[mi] = *(const bf16x8*)(As + (wr * 64 + mi * 16 + lr) * 64 + cs * 8);
            #pragma unroll
            for (int nj = 0; nj < 4; ++nj)
                bfr[nj] = *(const bf16x8*)(Bs + (wc * 64 + nj * 16 + lr) * 64 + cs * 8);
            #pragma unroll
            for (int mi = 0; mi < 4; ++mi)
                #pragma unroll
                for (int nj = 0; nj < 4; ++nj)
                    acc[mi][nj] = __builtin_amdgcn_mfma_f32_16x16x32_bf16(af[mi], bfr[nj], acc[mi][nj], 0, 0, 0);
        }
        __syncthreads();
    }

    const int mat = nt >> 2;
    const int hp  = nt & 3;
    if (mat < 2) {
        u16* Ob = (mat == 0) ? Qb : Kb;
        const float osc = (mat == 0) ? QSCALE : 1.0f;
        #pragma unroll
        for (int mi = 0; mi < 4; ++mi) {
            const int gmb = m0 + wr * 64 + mi * 16 + lh * 4;
            const int b = gmb >> 12;
            #pragma unroll
            for (int rr = 0; rr < 4; ++rr) {
                const int t = (gmb + rr) & 4095;
                const int n = t >> 2, r = t & 3;
                #pragma unroll
                for (int nj = 0; nj < 4; ++nj) {
                    const int c  = wc * 64 + nj * 16 + lr;
                    const int h  = hp * 2 + (c >> 6);
                    const int dk = c & 63;
                    const size_t g = ((size_t)(b * NH + h)) * 4 + r;
                    Ob[(g * NPAD + n) * DHEAD + dk] = f2bf(acc[mi][nj][rr] * osc);
                }
            }
        }
    } else {
        // V: retile via LDS -> coalesced stores of V^T [g][dv][n]
        #pragma unroll
        for (int mi = 0; mi < 4; ++mi) {
            const int nrel = wr * 16 + mi * 4 + lh;
            #pragma unroll
            for (int nj = 0; nj < 4; ++nj) {
                const int c = wc * 64 + nj * 16 + lr;
                #pragma unroll
                for (int rr = 0; rr < 4; ++rr)
                    smem[c * 132 + rr * 32 + nrel] = f2bf(acc[mi][nj][rr]);
            }
        }
        __syncthreads();
        const int b  = m0 >> 12;
        const int nb = (m0 & 4095) >> 2;
        #pragma unroll
        for (int e = 0; e < 2; ++e) {
            const int chunk = e * 256 + tid;
            const int c = chunk & 127, r = chunk >> 7;
            const int h  = hp * 2 + (c >> 6);
            const int dv = c & 63;
            const size_t g = ((size_t)(b * NH + h)) * 4 + r;
            u16* dst = Vb + (g * DHEAD + dv) * NPAD + nb;
            const u16* src = smem + c * 132 + r * 32;
            alignas(16) u16 tmp[32];
            #pragma unroll
            for (int q8 = 0; q8 < 8; ++q8)
                *(u16x4*)&tmp[q8 * 4] = *(const u16x4*)(src + q8 * 4);
            #pragma unroll
            for (int q16 = 0; q16 < 4; ++q16)
                *(u16x8*)(dst + q16 * 8) = *(const u16x8*)&tmp[q16 * 8];
        }
    }
}

// ---------------------------------------------------------------------------
// Flash attention per (b,h,r): 256 queries/block, 8 waves x 32 q-rows,
// 32x32x16 MFMA, swapped QK^T => q is lane-local; P stays in registers.
// Grid (64 g, 4 qblk) = 256 blocks, 2 blocks/CU, 16 waves/CU.
// ---------------------------------------------------------------------------
__global__ __launch_bounds__(512, 4) void attn_kernel(
    const u16* __restrict__ Qb, const u16* __restrict__ Kb, const u16* __restrict__ Vb,
    float* __restrict__ out)
{
    const int g  = blockIdx.x;          // ((b*8+h)*4+r): blocks sharing g -> same XCD
    const int b  = g >> 5;
    const int h  = (g >> 2) & 7;
    const int r  = g & 3;
    const int q0 = blockIdx.y * 256;
    const int tid = threadIdx.x;
    const int w  = tid >> 6;            // 0..7
    const int l  = tid & 63;
    const int lr = l & 31;              // q within wave tile / dv / key row
    const int hi = l >> 5;              // half-wave

    const u16* Qg  = Qb + (size_t)g * NPAD * DHEAD;
    const u16* Kg  = Kb + (size_t)g * NPAD * DHEAD;
    const u16* Vtg = Vb + (size_t)g * DHEAD * NPAD;   // [dv][n]

    __shared__ u16 KV[2][2][4096];   // [buf][K/V][64 rows][8 slots][8 u16]

    // staging: 512 thr cover 64 rows x 8 slots; source chunk XOR-swizzled
    const int srow = tid >> 3;              // 0..63
    const int ssch = (tid & 7) ^ (srow & 7);
    const u16* ksrc0 = Kg  + (size_t)srow * DHEAD + ssch * 8;
    const u16* vsrc0 = Vtg + (size_t)srow * NPAD  + ssch * 8;

    // Q fragments: lane -> q-row q0 + w*32 + lr, k-chunk c*16 + hi*8
    bf16x8 qa[4];
    {
        const u16* qrow = Qg + (size_t)(q0 + w * 32 + lr) * DHEAD + hi * 8;
        qa[0] = *(const bf16x8*)(qrow);
        qa[1] = *(const bf16x8*)(qrow + 16);
        qa[2] = *(const bf16x8*)(qrow + 32);
        qa[3] = *(const bf16x8*)(qrow + 48);
    }

    f32x16 o0 = zero16(), o1 = zero16();
    float Lown = 0.f;
    const int qw0 = q0 + w * 32;
    const int qg  = qw0 + lr;

    // prologue: stage tile 0 into buf 0 (one K + one V chunk per thread)
    gload16(ksrc0, &KV[0][0][w * 512]);
    gload16(vsrc0, &KV[0][1][w * 512]);

    for (int mt = 0; mt < 16; ++mt) {
        const int cur = mt & 1;
        if (mt < 15) {
            gload16(ksrc0 + (size_t)(mt + 1) * 64 * DHEAD, &KV[cur ^ 1][0][w * 512]);
            gload16(vsrc0 + (mt + 1) * 64,                 &KV[cur ^ 1][1][w * 512]);
            asm volatile("s_waitcnt vmcnt(2)" ::: "memory");
        } else {
            asm volatile("s_waitcnt vmcnt(0)" ::: "memory");
        }
        __builtin_amdgcn_s_barrier();

        const u16* Kbuf = KV[cur][0];
        const u16* Vbuf = KV[cur][1];

        // S^T = K Q^T : A = K-frag (rows=keys), B = Q-frag (cols=q)
        f32x16 sA = zero16(), sB = zero16();   // keys 0-31 / 32-63
        __builtin_amdgcn_s_setprio(1);
        #pragma unroll
        for (int c = 0; c < 4; ++c) {
            const int slot = (c * 2 + hi) ^ (lr & 7);
            bf16x8 kbA = *(const bf16x8*)(Kbuf + (lr * 8 + slot) * 8);
            bf16x8 kbB = *(const bf16x8*)(Kbuf + ((32 + lr) * 8 + slot) * 8);
            sA = __builtin_amdgcn_mfma_f32_32x32x16_bf16(kbA, qa[c], sA, 0, 0, 0);
            sB = __builtin_amdgcn_mfma_f32_32x32x16_bf16(kbB, qa[c], sB, 0, 0, 0);
        }
        __builtin_amdgcn_s_setprio(0);

        // softmax terms (fixed M=0, log2 space): p = exp2(s [+1 in window])
        const int m0 = mt * 64;
        const bool special = (m0 + 66 >= qw0) && (m0 <= qw0 + 34);
        if (!special) {
            #pragma unroll
            for (int reg = 0; reg < 16; ++reg) {
                sA[reg] = __builtin_amdgcn_exp2f(sA[reg]);
                sB[reg] = __builtin_amdgcn_exp2f(sB[reg]);
                Lown += sA[reg] + sB[reg];
            }
        } else {
            #pragma unroll
            for (int reg = 0; reg < 16; ++reg) {
                const int krel = (reg & 3) + 8 * (reg >> 2) + 4 * hi;
                {
                    const int dd = m0 + krel - qg;
                    float v = sA[reg];
                    if (dd >= -3 && dd <= 3) v += 1.0f;
                    sA[reg] = __builtin_amdgcn_exp2f(v);
                }
                {
                    const int dd = m0 + 32 + krel - qg;
                    float v = sB[reg];
                    if (dd >= -3 && dd <= 3) v += 1.0f;
                    sB[reg] = __builtin_amdgcn_exp2f(v);
                }
                Lown += sA[reg] + sB[reg];
            }
        }

        // pack P to bf16 pairs (keys 2k, 2k+1 within each half)
        u32 pkA[8], pkB[8];
        #pragma unroll
        for (int r2 = 0; r2 < 8; ++r2) {
            pkA[r2] = cvtpk(sA[2 * r2], sA[2 * r2 + 1]);
            pkB[r2] = cvtpk(sB[2 * r2], sB[2 * r2 + 1]);
        }

        // PV: assemble A-frag (P) in-register, B = V-frag from LDS
        __builtin_amdgcn_s_setprio(1);
        #pragma unroll
        for (int c = 0; c < 4; ++c) {
            const int c1 = c & 1;
            u32 p0, p1, p2, p3;
            if (c < 2) { p0 = pkA[4*c1]; p1 = pkA[4*c1+1]; p2 = pkA[4*c1+2]; p3 = pkA[4*c1+3]; }
            else       { p0 = pkB[4*c1]; p1 = pkB[4*c1+1]; p2 = pkB[4*c1+2]; p3 = pkB[4*c1+3]; }
            const u32 own0  = hi ? p2 : p0;
            const u32 own1  = hi ? p3 : p1;
            const u32 send0 = hi ? p0 : p2;
            const u32 send1 = hi ? p1 : p3;
            const u32 recv0 = (u32)__shfl_xor((int)send0, 32);
            const u32 recv1 = (u32)__shfl_xor((int)send1, 32);
            u32x4 paw;
            paw.x = hi ? recv0 : own0;
            paw.y = hi ? recv1 : own1;
            paw.z = hi ? own0  : recv0;
            paw.w = hi ? own1  : recv1;
            const bf16x8 pa = __builtin_bit_cast(bf16x8, paw);

            const int slot = (c * 2 + hi) ^ (lr & 7);
            bf16x8 vb0 = *(const bf16x8*)(Vbuf + (lr * 8 + slot) * 8);          // dv 0-31
            bf16x8 vb1 = *(const bf16x8*)(Vbuf + ((32 + lr) * 8 + slot) * 8);   // dv 32-63
            o0 = __builtin_amdgcn_mfma_f32_32x32x16_bf16(pa, vb0, o0, 0, 0, 0);
            o1 = __builtin_amdgcn_mfma_f32_32x32x16_bf16(pa, vb1, o1, 0, 0, 0);
        }
        __builtin_amdgcn_s_setprio(0);
        if (mt < 15) __syncthreads();   // reads of buf done before next overwrite
    }

    // epilogue: denominator = Lown(both halves) + zero-key (+1, doubled if
    // q>=1021) + OOB window slots (+coob); divide and store.
    const float Ltot = Lown + __shfl_xor(Lown, 32);
    const int coob = (qg < 3 ? 3 - qg : 0) + (qg > 1021 ? qg - 1021 : 0);
    const float inv = 1.0f / (Ltot + (float)(coob + 1 + (qg >= 1021 ? 1 : 0)));

    float iv[16];
    #pragma unroll
    for (int reg = 0; reg < 16; ++reg)
        iv[reg] = __shfl(inv, (reg & 3) + 8 * (reg >> 2) + 4 * hi);

    #pragma unroll
    for (int reg = 0; reg < 16; ++reg) {
        const int qrel = (reg & 3) + 8 * (reg >> 2) + 4 * hi;
        const int t = (q0 + w * 32 + qrel) * 4 + r;
        float* orow = out + ((size_t)b * LSEQ + t) * DMODEL + h * DHEAD;
        orow[lr]      = o0[reg] * iv[reg];
        orow[32 + lr] = o1[reg] * iv[reg];
    }
}

extern "C" void kernel_launch(void* const* d_in, const int* in_sizes, int n_in,
                              void* d_out, int out_size, void* d_ws, size_t ws_size,
                              hipStream_t stream) {
    const float* x  = (const float*)d_in[0];
    const float* Wq = (const float*)d_in[1];
    const float* Wk = (const float*)d_in[2];
    const float* Wv = (const float*)d_in[3];
    float* out = (float*)d_out;

    const size_t SZ = (size_t)BATCH * NH * 4 * NPAD * DHEAD;   // per-tensor elems
    u16* Qb = (u16*)d_ws;
    u16* Kb = Qb + SZ;
    u16* Vb = Kb + SZ;

    // scratch for bf16 x and transposed W lives in d_out (overwritten by attn)
    u16* xb = (u16*)d_out;                       // 8192*512 u16
    u16* Wt = xb + (size_t)8192 * 512;           // 1536*512 u16

    prep_kernel<<<2240, 256, 0, stream>>>(x, Wq, Wk, Wv, xb, Wt);

    gemm_kernel<<<768, 256, 0, stream>>>(xb, Wt, Qb, Kb, Vb);

    dim3 ga(64, 4);
    attn_kernel<<<ga, 512, 0, stream>>>(Qb, Kb, Vb, out);
}